// Round 13
// baseline (1953.482 us; speedup 1.0000x reference)
//
#include <hip/hip_runtime.h>
#include <math.h>

#define TPB 256

typedef __attribute__((ext_vector_type(8))) short bf16x8;
typedef __attribute__((ext_vector_type(4))) float f32x4;
typedef __attribute__((ext_vector_type(2))) float f32x2;

// ---------------- workspace layout ----------------
// aux (fp32), float offsets:
#define OFF_PN2   0          // 256
#define OFF_GN2   256        // 256
#define OFF_GATE  512        // 256
#define OFF_TEMP  768        // 1
#define OFF_WEFF  1024       // 2560
#define OFF_W1T   3584       // 2400 fp32: w1t[tap<75][oc<32]
// bf16 weight tables (byte offsets):
#define OFF_W2T_BYTES 737280ul    // 9*64*32   bf16
#define OFF_W3T_BYTES 786432ul    // 9*128*64  bf16
#define OFF_W4T_BYTES 983040ul    // 9*256*128 bf16
#define OFF_EWT_BYTES 2097152ul   // ewt[n=256][k=16384] bf16 = 8 MiB
// post-stage bf16 tables:
#define OFF_NFWT_BYTES 10485760ul // nfwt[n=256][k=256] bf16 = 128 KiB
#define OFF_PJD_BYTES  10616832ul // protos[j][d] bf16
#define OFF_GJD_BYTES  10747904ul // grid[j][d] bf16
#define OFF_PTB_BYTES  10878976ul // protosT[d][j] bf16
// big regions (byte offsets):
#define OFF_A_BYTES   12582912ul
#define OFF_B_BYTES   (OFF_A_BYTES + 67108864ul)
#define OFF_Z0_BYTES  (OFF_B_BYTES + 33554432ul)
// total ~112 MiB

// ---------------- bf16 helpers ----------------
__device__ __forceinline__ float bf2f(ushort u) {
  return __uint_as_float(((unsigned)u) << 16);
}
__device__ __forceinline__ ushort f2bf(float f) {   // RNE
  unsigned x = __float_as_uint(f);
  return (ushort)((x + 0x7fffu + ((x >> 16) & 1u)) >> 16);
}
__device__ __forceinline__ unsigned pack2(float a, float b) {
  return (unsigned)f2bf(a) | ((unsigned)f2bf(b) << 16);
}

// async global->LDS, 16B per lane; lds dest = wave-uniform base + lane*16
__device__ __forceinline__ void gload_lds16(const ushort* g, ushort* l) {
  __builtin_amdgcn_global_load_lds(
      (const __attribute__((address_space(1))) unsigned int*)g,
      (__attribute__((address_space(3))) unsigned int*)l, 16, 0, 0);
}

// ---------------- block reductions ----------------
__device__ __forceinline__ float block_sum(float v, float* red) {
  #pragma unroll
  for (int off = 32; off > 0; off >>= 1) v += __shfl_down(v, off, 64);
  int wid = threadIdx.x >> 6;
  __syncthreads();
  if ((threadIdx.x & 63) == 0) red[wid] = v;
  __syncthreads();
  return red[0] + red[1] + red[2] + red[3];
}

// ---------------- setup (+ zero z0 for split-K atomics) ----------------
__global__ void __launch_bounds__(256) k_setup(const float* __restrict__ protos,
    const float* __restrict__ gridp, const float* __restrict__ gate_logits,
    const float* __restrict__ temp_raw, const float* __restrict__ clf_w,
    float* __restrict__ ws, float* __restrict__ z0) {
  __shared__ float red[4];
  int b = blockIdx.x, t = threadIdx.x;
  #pragma unroll
  for (int u = 0; u < 16; ++u) z0[(size_t)u*65536 + b*256 + t] = 0.f;
  float pv = protos[b*256 + t];
  float gv = gridp [b*256 + t];
  float sp = block_sum(pv*pv, red);
  float sg = block_sum(gv*gv, red);
  if (t == 0) {
    ws[OFF_PN2 + b] = sp;
    ws[OFF_GN2 + b] = sg;
    ws[OFF_GATE + b] = 1.f/(1.f + expf(-gate_logits[b]));
  }
  if (b == 0) {
    for (int i = t; i < 2560; i += TPB) {
      int d = i/10, c = i%10;
      ws[OFF_WEFF + i] = clf_w[d*10+c] + clf_w[(256+d)*10+c]
                       + clf_w[(512+d)*10+c] + clf_w[(768+d)*10+c];
    }
    if (t == 0) {
      float s = 1.f/(1.f + expf(-temp_raw[0]));
      ws[OFF_TEMP] = s*(1.f - 0.001f) + 0.001f;
    }
  }
}

// ---------------- prep: weight tables (conv1 fp32-T, conv2/3/4 bf16) ----------------
__global__ void __launch_bounds__(256) k_prep(const float* __restrict__ w1,
    const float* __restrict__ w2, const float* __restrict__ w3,
    const float* __restrict__ w4, float* __restrict__ w1t,
    ushort* __restrict__ w2t, ushort* __restrict__ w3t, ushort* __restrict__ w4t) {
  int idx = blockIdx.x*256 + threadIdx.x;
  if (idx < 2400) {
    int tap = idx >> 5, oc = idx & 31;
    w1t[idx] = w1[oc*75 + tap];
  }
  if (idx < 18432) {
    int tap = idx >> 11, r = idx & 2047, oc = r >> 5, ic = r & 31;
    w2t[idx] = f2bf(w2[oc*288 + ic*9 + tap]);
  }
  if (idx < 73728) {
    int tap = idx >> 13, r = idx & 8191, oc = r >> 6, ic = r & 63;
    w3t[idx] = f2bf(w3[oc*576 + ic*9 + tap]);
  }
  if (idx < 294912) {
    int tap = idx >> 15, r = idx & 32767, oc = r >> 7, ic = r & 127;
    w4t[idx] = f2bf(w4[oc*1152 + ic*9 + tap]);
  }
}

// ---------------- prep2: bf16 tables for the post stage ----------------
__global__ void __launch_bounds__(256) k_prep2(const float* __restrict__ nfw,
    const float* __restrict__ protos, const float* __restrict__ gridp,
    ushort* __restrict__ nfwt, ushort* __restrict__ pjd,
    ushort* __restrict__ gjd, ushort* __restrict__ ptb) {
  int idx = blockIdx.x*256 + threadIdx.x;   // 65536
  int a = idx >> 8, b = idx & 255;
  nfwt[idx] = f2bf(nfw[b*256 + a]);     // [n][k] = nfw[k][n]
  pjd [idx] = f2bf(protos[idx]);        // [j][d]
  gjd [idx] = f2bf(gridp[idx]);         // [j][d]
  ptb [idx] = f2bf(protos[b*256 + a]);  // [d][j] = protos[j][d]
}

// ---------------- transpose enc_w -> ewt[n<256][k<16384] bf16 ----------------
__global__ void __launch_bounds__(256) k_trans(const float* __restrict__ ew,
    ushort* __restrict__ ewt) {
  __shared__ float tile[64][65];
  int kb = blockIdx.x, nb = blockIdx.y, t = threadIdx.x;
  #pragma unroll
  for (int i = 0; i < 16; ++i) {
    int idx = t + i*256, k = idx >> 6, n = idx & 63;
    tile[k][n] = ew[(size_t)(kb*64 + k)*256 + nb*64 + n];
  }
  __syncthreads();
  #pragma unroll
  for (int i = 0; i < 16; ++i) {
    int idx = t + i*256, n = idx >> 6, k = idx & 63;
    ewt[(size_t)(nb*64 + n)*16384 + kb*64 + k] = f2bf(tile[k][n]);
  }
}

// ---------------- conv1+conv2 fused v4: minimal LDS (xs only, 23.1 KB) ----------
__global__ void __launch_bounds__(256) k_conv12(const float* __restrict__ x,
    const float* __restrict__ w1t, const float* __restrict__ b1,
    const ushort* __restrict__ w2t, const float* __restrict__ b2,
    ushort* __restrict__ h2c) {
  __shared__ ushort xs[17*17*40];   // 23120 B only
  int b = blockIdx.x, t = threadIdx.x;
  for (int i = t; i < 5780; i += TPB) ((unsigned*)xs)[i] = 0u;
  const float* xb = x + (size_t)b*3072;

  if (t < 225) {               // conv1: one px per thread, all 32 oc, packed f32
    int oy = t/15, ox = t%15;
    f32x2 acc[16];
    #pragma unroll
    for (int o = 0; o < 16; ++o) acc[o] = *(const f32x2*)&b1[2*o];
    for (int ic = 0; ic < 3; ++ic) {
      const int icb = ic*1024;
      #pragma unroll
      for (int ky = 0; ky < 5; ++ky) {
        int iy = 2*oy - 1 + ky;
        bool rok = (unsigned)iy < 32u;
        int rbase = icb + (rok ? iy*32 : 0);
        #pragma unroll
        for (int kx = 0; kx < 5; ++kx) {
          int ix = 2*ox - 1 + kx;
          bool ok = rok && ((unsigned)ix < 32u);
          float xv = xb[rbase + (ok ? ix : 0)];
          xv = ok ? xv : 0.f;
          f32x2 xv2 = {xv, xv};
          const float* wrow = &w1t[(ic*25 + ky*5 + kx)*32];   // wave-uniform -> s_load
          #pragma unroll
          for (int g = 0; g < 8; ++g) {
            f32x2 wlo = {wrow[4*g+0], wrow[4*g+1]};
            f32x2 whi = {wrow[4*g+2], wrow[4*g+3]};
            acc[2*g]   += xv2*wlo;
            acc[2*g+1] += xv2*whi;
          }
        }
      }
    }
    unsigned pk[16];
    #pragma unroll
    for (int g = 0; g < 16; ++g)
      pk[g] = pack2(fmaxf(acc[g].x, 0.f), fmaxf(acc[g].y, 0.f));
    ushort* cell = &xs[((oy+1)*17 + (ox+1))*40];
    #pragma unroll
    for (int q = 0; q < 4; ++q) *(uint4*)(cell + q*8) = ((uint4*)pk)[q];
  }
  __syncthreads();

  // conv2 MFMA (swapped: oc-in-regs): wave w -> oc [w*16, w*16+16)
  const int lane = t & 63, w = t >> 6;
  const int quad = lane >> 4, row16 = lane & 15;
  f32x4 acc2[4];
  #pragma unroll
  for (int mt = 0; mt < 4; ++mt) acc2[mt] = (f32x4)0.f;
  #pragma unroll
  for (int ky = 0; ky < 3; ++ky)
    #pragma unroll
    for (int kx = 0; kx < 3; ++kx) {
      int tap = ky*3 + kx;
      bf16x8 bf = *(const bf16x8*)&w2t[tap*2048 + (w*16 + row16)*32 + quad*8];
      #pragma unroll
      for (int mt = 0; mt < 4; ++mt) {
        int px = mt*16 + row16;
        int iy = 2*(px >> 3) + ky, ix = 2*(px & 7) + kx;
        bf16x8 af = *(const bf16x8*)&xs[(iy*17 + ix)*40 + quad*8];
        acc2[mt] = __builtin_amdgcn_mfma_f32_16x16x32_bf16(bf, af, acc2[mt], 0, 0, 0);
      }
    }
  float4 bb = *(const float4*)&b2[w*16 + quad*4];
  #pragma unroll
  for (int mt = 0; mt < 4; ++mt) {
    int px = mt*16 + row16;
    uint2 dd;
    dd.x = pack2(fmaxf(acc2[mt][0] + bb.x, 0.f), fmaxf(acc2[mt][1] + bb.y, 0.f));
    dd.y = pack2(fmaxf(acc2[mt][2] + bb.z, 0.f), fmaxf(acc2[mt][3] + bb.w, 0.f));
    *(uint2*)&h2c[(size_t)b*4096 + px*64 + w*16 + quad*4] = dd;
  }
}

// ---------------- conv3+conv4 fused v5: 2 imgs/block, B shared, xp/h3p ALIASED ----
// One LDS buffer (34816 B): xp view [img][64 px][72] lives in the low 18432 B;
// after conv3's last xp read (+barrier) the SAME buffer is reused as
// h3p [img][64 px][136]. 34.8 KB -> 4 blocks/CU (was 53.2 KB -> 2).
__global__ void __launch_bounds__(256, 4) k_conv34(const ushort* __restrict__ h2c,
    const float* __restrict__ b3, const float* __restrict__ b4,
    const ushort* __restrict__ w3t, const ushort* __restrict__ w4t,
    ushort* __restrict__ h4c, int img_base) {
  __shared__ ushort buf[2*8704];    // 34816 B total
  ushort* xp  = buf;                // [img*4608 + px*72 + ic]   (18432 B)
  ushort* h3p = buf;                // [img*8704 + px*136 + oc]  (34816 B, after alias barrier)
  const int bl = blockIdx.x, t = threadIdx.x;
  #pragma unroll
  for (int u = 0; u < 4; ++u) {
    int i = t + u*256;
    int img = i >> 9, r = i & 511, px = r >> 3, icq = r & 7;
    bf16x8 v = *(const bf16x8*)&h2c[(size_t)(img_base + bl*2 + img)*4096 + px*64 + icq*8];
    *(bf16x8*)&xp[img*4608 + px*72 + icq*8] = v;
  }
  __syncthreads();

  const int lane = t & 63, oq = t >> 6;
  const int quad = lane >> 4, row16 = lane & 15;
  const bf16x8 zr = (bf16x8)(short)0;
  int aoy[8], aox[8], ioff3[8], ioff4[8];
  #pragma unroll
  for (int mt = 0; mt < 8; ++mt) {
    int px = (mt & 3)*16 + row16;
    aoy[mt] = px >> 3; aox[mt] = px & 7;
    ioff3[mt] = (mt >> 2)*4608;
    ioff4[mt] = (mt >> 2)*8704;
  }

  // ---- conv3 (reads xp view) ----
  f32x4 c3[8][2];
  #pragma unroll
  for (int mt = 0; mt < 8; ++mt) { c3[mt][0] = (f32x4)0.f; c3[mt][1] = (f32x4)0.f; }
  const ushort* wb3 = w3t + (oq*32 + row16)*64 + quad*8;
  bf16x8 r3a = *(const bf16x8*)(wb3);
  bf16x8 r3b = *(const bf16x8*)(wb3 + 1024);
  for (int tap = 0; tap < 9; ++tap, wb3 += 8192) {
    int ky = tap/3, kx = tap - 3*ky;
    int ab[8]; bool vv[8];
    #pragma unroll
    for (int mt = 0; mt < 8; ++mt) {
      int iy = aoy[mt] + ky - 1, ix = aox[mt] + kx - 1;
      vv[mt] = ((unsigned)iy < 8u) && ((unsigned)ix < 8u);
      int pxv = vv[mt] ? (iy*8 + ix) : 0;
      ab[mt] = ioff3[mt] + pxv*72 + quad*8;
    }
    #pragma unroll
    for (int ks = 0; ks < 2; ++ks) {
      const ushort* wn = wb3 + ((ks == 1) ? 8192 : 32);
      bf16x8 n0 = *(const bf16x8*)(wn);
      bf16x8 n1 = *(const bf16x8*)(wn + 1024);
      #pragma unroll
      for (int mt = 0; mt < 8; ++mt) {
        bf16x8 ax = *(const bf16x8*)&xp[ab[mt] + ks*32];
        ax = vv[mt] ? ax : zr;
        c3[mt][0] = __builtin_amdgcn_mfma_f32_16x16x32_bf16(r3a, ax, c3[mt][0], 0, 0, 0);
        c3[mt][1] = __builtin_amdgcn_mfma_f32_16x16x32_bf16(r3b, ax, c3[mt][1], 0, 0, 0);
      }
      r3a = n0; r3b = n1;
    }
  }
  __syncthreads();   // ALIAS BARRIER: all xp reads complete before h3p overwrites buf
  #pragma unroll
  for (int nt = 0; nt < 2; ++nt) {
    float4 bb = *(const float4*)&b3[oq*32 + nt*16 + quad*4];
    #pragma unroll
    for (int mt = 0; mt < 8; ++mt) {
      int px = (mt & 3)*16 + row16;
      uint2 dd;
      dd.x = pack2(fmaxf(c3[mt][nt][0] + bb.x, 0.f), fmaxf(c3[mt][nt][1] + bb.y, 0.f));
      dd.y = pack2(fmaxf(c3[mt][nt][2] + bb.z, 0.f), fmaxf(c3[mt][nt][3] + bb.w, 0.f));
      *(uint2*)&h3p[ioff4[mt] + px*136 + oq*32 + nt*16 + quad*4] = dd;
    }
  }
  __syncthreads();

  // ---- conv4 (reads h3p view) ----
  f32x4 c4[8][4];
  #pragma unroll
  for (int mt = 0; mt < 8; ++mt)
    #pragma unroll
    for (int nt = 0; nt < 4; ++nt) c4[mt][nt] = (f32x4)0.f;
  const ushort* wb4 = w4t + (oq*64 + row16)*128 + quad*8;
  bf16x8 r4[4];
  #pragma unroll
  for (int nt = 0; nt < 4; ++nt) r4[nt] = *(const bf16x8*)(wb4 + nt*2048);
  for (int tap = 0; tap < 9; ++tap, wb4 += 32768) {
    int ky = tap/3, kx = tap - 3*ky;
    int ab[8]; bool vv[8];
    #pragma unroll
    for (int mt = 0; mt < 8; ++mt) {
      int iy = aoy[mt] + ky - 1, ix = aox[mt] + kx - 1;
      vv[mt] = ((unsigned)iy < 8u) && ((unsigned)ix < 8u);
      int pxv = vv[mt] ? (iy*8 + ix) : 0;
      ab[mt] = ioff4[mt] + pxv*136 + quad*8;
    }
    #pragma unroll
    for (int ks = 0; ks < 4; ++ks) {
      const ushort* wn = wb4 + ((ks == 3) ? 32768 : (ks + 1)*32);
      bf16x8 nx[4];
      #pragma unroll
      for (int nt = 0; nt < 4; ++nt) nx[nt] = *(const bf16x8*)(wn + nt*2048);
      #pragma unroll
      for (int mt = 0; mt < 8; ++mt) {
        bf16x8 ax = *(const bf16x8*)&h3p[ab[mt] + ks*32];
        ax = vv[mt] ? ax : zr;
        #pragma unroll
        for (int nt = 0; nt < 4; ++nt)
          c4[mt][nt] = __builtin_amdgcn_mfma_f32_16x16x32_bf16(ax, r4[nt], c4[mt][nt], 0, 0, 0);
      }
      #pragma unroll
      for (int nt = 0; nt < 4; ++nt) r4[nt] = nx[nt];
    }
  }
  #pragma unroll
  for (int nt = 0; nt < 4; ++nt) {
    int oc = oq*64 + nt*16 + row16;
    float bv = b4[oc];
    #pragma unroll
    for (int mt = 0; mt < 8; ++mt) {
      int ig = bl*2 + (mt >> 2);
      int px0 = (mt & 3)*16 + quad*4;
      uint2 dd;
      dd.x = pack2(fmaxf(c4[mt][nt][0] + bv, 0.f), fmaxf(c4[mt][nt][1] + bv, 0.f));
      dd.y = pack2(fmaxf(c4[mt][nt][2] + bv, 0.f), fmaxf(c4[mt][nt][3] + bv, 0.f));
      *(uint2*)&h4c[(size_t)ig*16384 + oc*64 + px0] = dd;
    }
  }
}

// ---------------- enc: z0 += h4c @ ewt^T, MFMA bf16, split-K=16, 128x128 tiles ------
__global__ void __launch_bounds__(256) k_enc(const ushort* __restrict__ h4c,
    const ushort* __restrict__ ewt, float* __restrict__ z0, int img_base) {
  __shared__ ushort a_s[128*64];   // 16 KB
  __shared__ ushort b_s[128*64];   // 16 KB
  const int t = threadIdx.x, bx = blockIdx.x;
  const int slice = bx & 15;
  const int mb = (bx >> 4) & 15;
  const int nb = bx >> 8;
  const int M0 = mb*128, N0 = nb*128;
  const int kbase = slice*1024;
  const int lane = t & 63, wv = t >> 6;
  const int quad = lane >> 4, row16 = lane & 15;
  const int mrow0 = (wv & 1)*64, ncol0 = (wv >> 1)*64;
  const int sr = lane >> 3, sp = lane & 7;

  f32x4 acc[4][4];
  #pragma unroll
  for (int mt = 0; mt < 4; ++mt)
    #pragma unroll
    for (int nt = 0; nt < 4; ++nt) acc[mt][nt] = (f32x4)0.f;

  for (int kt = 0; kt < 16; ++kt) {
    const int k0 = kbase + kt*64;
    __syncthreads();
    #pragma unroll
    for (int u = 0; u < 4; ++u) {
      int r = wv*32 + u*8 + sr;
      int c = sp ^ (r & 7);
      gload_lds16(&h4c[(size_t)(M0 + r)*16384 + k0 + c*8], &a_s[(wv*32 + u*8)*64]);
      gload_lds16(&ewt[(size_t)(N0 + r)*16384 + k0 + c*8], &b_s[(wv*32 + u*8)*64]);
    }
    __syncthreads();
    #pragma unroll
    for (int ks = 0; ks < 2; ++ks) {
      bf16x8 af[4], bf[4];
      #pragma unroll
      for (int mt = 0; mt < 4; ++mt) {
        int r = mrow0 + mt*16 + row16;
        int p = (ks*4 + quad) ^ (r & 7);
        af[mt] = *(const bf16x8*)&a_s[r*64 + p*8];
      }
      #pragma unroll
      for (int nt = 0; nt < 4; ++nt) {
        int r = ncol0 + nt*16 + row16;
        int p = (ks*4 + quad) ^ (r & 7);
        bf[nt] = *(const bf16x8*)&b_s[r*64 + p*8];
      }
      #pragma unroll
      for (int mt = 0; mt < 4; ++mt)
        #pragma unroll
        for (int nt = 0; nt < 4; ++nt)
          acc[mt][nt] = __builtin_amdgcn_mfma_f32_16x16x32_bf16(af[mt], bf[nt], acc[mt][nt], 0, 0, 0);
    }
  }
  #pragma unroll
  for (int mt = 0; mt < 4; ++mt) {
    int mrow = M0 + mrow0 + mt*16 + quad*4;
    #pragma unroll
    for (int nt = 0; nt < 4; ++nt) {
      int col = N0 + ncol0 + nt*16 + row16;
      #pragma unroll
      for (int r = 0; r < 4; ++r)
        atomicAdd(&z0[(size_t)(img_base + mrow + r)*256 + col], acc[mt][nt][r]);
    }
  }
}

// ---------------- post v2: fully-fused MFMA tail, 16 img/block, grid 256 ----------
__global__ void __launch_bounds__(256) k_post2(const float* __restrict__ z0,
    const float* __restrict__ enc_b, const float* __restrict__ nfb,
    const ushort* __restrict__ nfwt, const ushort* __restrict__ pjd,
    const ushort* __restrict__ gjd, const ushort* __restrict__ ptb,
    const float* __restrict__ ws, const float* __restrict__ clf_b,
    float* __restrict__ out) {
  __shared__ ushort zin[16*264];   // 8448 B
  __shared__ ushort zS [16*264];   // 8448 B
  __shared__ float  Df [16*264];   // 16896 B (l / blended)
  __shared__ ushort wS [16*264];   // 8448 B
  __shared__ float  z2s[16];
  const int t = threadIdx.x, bx = blockIdx.x;
  const int img0 = bx*16;
  #pragma unroll
  for (int u = 0; u < 16; ++u) {
    int i = t + u*256;
    int im = i >> 8, d = i & 255;
    zin[im*264 + d] = f2bf(z0[(size_t)(img0 + im)*256 + d] + enc_b[d]);
  }
  __syncthreads();

  const int lane = t & 63, w = t >> 6;
  const int quad = lane >> 4, row16 = lane & 15;
  const int n0 = w*64;

  // ---- phase 1: z = zin @ nfw^T + nfb ----
  f32x4 zC[4];
  #pragma unroll
  for (int nt = 0; nt < 4; ++nt) zC[nt] = (f32x4)0.f;
  #pragma unroll
  for (int ks = 0; ks < 8; ++ks) {
    bf16x8 az = *(const bf16x8*)&zin[row16*264 + ks*32 + quad*8];
    #pragma unroll
    for (int nt = 0; nt < 4; ++nt) {
      bf16x8 bw = *(const bf16x8*)&nfwt[(n0 + nt*16 + row16)*256 + ks*32 + quad*8];
      zC[nt] = __builtin_amdgcn_mfma_f32_16x16x32_bf16(az, bw, zC[nt], 0, 0, 0);
    }
  }
  #pragma unroll
  for (int nt = 0; nt < 4; ++nt) {
    int n = n0 + nt*16 + row16;
    float nb = nfb[n];
    #pragma unroll
    for (int r = 0; r < 4; ++r)
      zS[(quad*4 + r)*264 + n] = f2bf(zC[nt][r] + nb);
  }
  __syncthreads();

  {
    int im = t >> 4, jg = t & 15;
    float s = 0.f;
    #pragma unroll
    for (int q = 0; q < 16; ++q) {
      float v = bf2f(zS[im*264 + jg + 16*q]);
      s += v*v;
    }
    #pragma unroll
    for (int off = 8; off; off >>= 1) s += __shfl_xor(s, off, 16);
    if (jg == 0) z2s[im] = s;
  }
  __syncthreads();

  // ---- phase 2: dp/dg = z @ protos^T / grid^T -> logits l ----
  f32x4 dpC[4], dgC[4];
  #pragma unroll
  for (int nt = 0; nt < 4; ++nt) { dpC[nt] = (f32x4)0.f; dgC[nt] = (f32x4)0.f; }
  #pragma unroll
  for (int ks = 0; ks < 8; ++ks) {
    bf16x8 az = *(const bf16x8*)&zS[row16*264 + ks*32 + quad*8];
    #pragma unroll
    for (int nt = 0; nt < 4; ++nt) {
      int j = n0 + nt*16 + row16;
      bf16x8 bp = *(const bf16x8*)&pjd[j*256 + ks*32 + quad*8];
      bf16x8 bg = *(const bf16x8*)&gjd[j*256 + ks*32 + quad*8];
      dpC[nt] = __builtin_amdgcn_mfma_f32_16x16x32_bf16(az, bp, dpC[nt], 0, 0, 0);
      dgC[nt] = __builtin_amdgcn_mfma_f32_16x16x32_bf16(az, bg, dgC[nt], 0, 0, 0);
    }
  }
  {
    float temp = ws[OFF_TEMP];
    #pragma unroll
    for (int nt = 0; nt < 4; ++nt) {
      int j = n0 + nt*16 + row16;
      float pn = ws[OFF_PN2 + j], gn = ws[OFF_GN2 + j];
      #pragma unroll
      for (int r = 0; r < 4; ++r) {
        int im = quad*4 + r;
        float z2 = z2s[im];
        float d2p = z2 + pn - 2.f*dpC[nt][r];
        float d2g = z2 + gn - 2.f*dgC[nt][r];
        float l = -(sqrtf(fmaxf(d2p, 0.f)) + sqrtf(fmaxf(d2g, 0.f)))/temp;
        Df[im*264 + j] = l;
      }
    }
  }
  __syncthreads();

  // ---- softmax + gate + renorm -> wS bf16 ----
  {
    int im = t >> 4, jg = t & 15;
    float m = -1e30f;
    #pragma unroll
    for (int q = 0; q < 16; ++q) m = fmaxf(m, Df[im*264 + jg + 16*q]);
    #pragma unroll
    for (int off = 8; off; off >>= 1) m = fmaxf(m, __shfl_xor(m, off, 16));
    float E = 0.f, S = 0.f, ev[16], gv[16];
    #pragma unroll
    for (int q = 0; q < 16; ++q) {
      int j = jg + 16*q;
      float e = expf(Df[im*264 + j] - m);
      float g = ws[OFF_GATE + j];
      ev[q] = e; gv[q] = g;
      E += e; S += e*g;
    }
    #pragma unroll
    for (int off = 8; off; off >>= 1) {
      E += __shfl_xor(E, off, 16);
      S += __shfl_xor(S, off, 16);
    }
    float inv = 1.f/(S + 1e-8f*E);
    #pragma unroll
    for (int q = 0; q < 16; ++q)
      wS[im*264 + jg + 16*q] = f2bf(ev[q]*gv[q]*inv);
  }
  __syncthreads();

  // ---- phase 3: blended = w @ protos ----
  f32x4 blC[4];
  #pragma unroll
  for (int nt = 0; nt < 4; ++nt) blC[nt] = (f32x4)0.f;
  #pragma unroll
  for (int ks = 0; ks < 8; ++ks) {
    bf16x8 aw = *(const bf16x8*)&wS[row16*264 + ks*32 + quad*8];
    #pragma unroll
    for (int nt = 0; nt < 4; ++nt) {
      bf16x8 bp = *(const bf16x8*)&ptb[(n0 + nt*16 + row16)*256 + ks*32 + quad*8];
      blC[nt] = __builtin_amdgcn_mfma_f32_16x16x32_bf16(aw, bp, blC[nt], 0, 0, 0);
    }
  }
  #pragma unroll
  for (int nt = 0; nt < 4; ++nt) {
    int d = n0 + nt*16 + row16;
    #pragma unroll
    for (int r = 0; r < 4; ++r)
      Df[(quad*4 + r)*264 + d] = blC[nt][r];
  }
  __syncthreads();

  if (t < 160) {
    int im = t/10, c = t - im*10;
    float s = clf_b[c];
    for (int d = 0; d < 256; ++d)
      s += Df[im*264 + d]*ws[OFF_WEFF + d*10 + c];
    out[(size_t)(img0 + im)*10 + c] = s;
  }
}

extern "C" void kernel_launch(void* const* d_in, const int* in_sizes, int n_in,
                              void* d_out, int out_size, void* d_ws, size_t ws_size,
                              hipStream_t stream) {
  (void)in_sizes; (void)n_in; (void)out_size; (void)ws_size;
  const float* x      = (const float*)d_in[0];
  const float* c1w    = (const float*)d_in[2];
  const float* c1b    = (const float*)d_in[3];
  const float* c2w    = (const float*)d_in[4];
  const float* c2b    = (const float*)d_in[5];
  const float* c3w    = (const float*)d_in[6];
  const float* c3b    = (const float*)d_in[7];
  const float* c4w    = (const float*)d_in[8];
  const float* c4b    = (const float*)d_in[9];
  const float* encw   = (const float*)d_in[10];
  const float* encb   = (const float*)d_in[11];
  // d_in[12..17] dead: softmax over a single node == 1 exactly
  const float* clfw   = (const float*)d_in[18];
  const float* clfb   = (const float*)d_in[19];
  const float* nfw    = (const float*)d_in[20];
  const float* nfb    = (const float*)d_in[21];
  const float* protos = (const float*)d_in[22];
  const float* gridp  = (const float*)d_in[23];
  const float* traw   = (const float*)d_in[24];
  const float* gatel  = (const float*)d_in[25];

  float*  ws   = (float*)d_ws;
  float*  w1t  = ws + OFF_W1T;
  ushort* w2t  = (ushort*)((char*)d_ws + OFF_W2T_BYTES);
  ushort* w3t  = (ushort*)((char*)d_ws + OFF_W3T_BYTES);
  ushort* w4t  = (ushort*)((char*)d_ws + OFF_W4T_BYTES);
  ushort* ewt  = (ushort*)((char*)d_ws + OFF_EWT_BYTES);
  ushort* nfwt = (ushort*)((char*)d_ws + OFF_NFWT_BYTES);
  ushort* pjd  = (ushort*)((char*)d_ws + OFF_PJD_BYTES);
  ushort* gjd  = (ushort*)((char*)d_ws + OFF_GJD_BYTES);
  ushort* ptb  = (ushort*)((char*)d_ws + OFF_PTB_BYTES);
  ushort* h4c  = (ushort*)((char*)d_ws + OFF_A_BYTES);
  ushort* h2c  = (ushort*)((char*)d_ws + OFF_B_BYTES);
  float*  z0   = (float*) ((char*)d_ws + OFF_Z0_BYTES);
  float*  out  = (float*)d_out;

  hipLaunchKernelGGL(k_setup, dim3(256),  dim3(TPB), 0, stream, protos, gridp, gatel, traw, clfw, ws, z0);
  hipLaunchKernelGGL(k_prep,  dim3(1152), dim3(TPB), 0, stream, c1w, c2w, c3w, c4w, w1t, w2t, w3t, w4t);
  hipLaunchKernelGGL(k_prep2, dim3(256),  dim3(TPB), 0, stream, nfw, protos, gridp, nfwt, pjd, gjd, ptb);
  hipLaunchKernelGGL(k_trans, dim3(256, 4), dim3(TPB), 0, stream, encw, ewt);
  hipLaunchKernelGGL(k_conv12, dim3(4096), dim3(TPB), 0, stream, x, w1t, c1b, w2t, c2b, h2c);
  for (int c = 0; c < 2; ++c) {
    hipLaunchKernelGGL(k_conv34, dim3(1024), dim3(TPB), 0, stream,
                       h2c, c3b, c4b, w3t, w4t, h4c, c*2048);
    hipLaunchKernelGGL(k_enc, dim3(512), dim3(TPB), 0, stream, h4c, ewt, z0, c*2048);
  }
  hipLaunchKernelGGL(k_post2, dim3(256), dim3(TPB), 0, stream,
                     z0, encb, nfb, nfwt, pjd, gjd, ptb, ws, clfb, out);
}

// Round 14
// 559.603 us; speedup vs baseline: 3.4908x; 3.4908x over previous
//
#include <hip/hip_runtime.h>
#include <math.h>

#define TPB 256

typedef __attribute__((ext_vector_type(8))) short bf16x8;
typedef __attribute__((ext_vector_type(4))) float f32x4;
typedef __attribute__((ext_vector_type(2))) float f32x2;

// ---------------- workspace layout ----------------
// aux (fp32), float offsets:
#define OFF_PN2   0          // 256
#define OFF_GN2   256        // 256
#define OFF_GATE  512        // 256
#define OFF_TEMP  768        // 1
#define OFF_WEFF  1024       // 2560
#define OFF_W1T   3584       // 2400 fp32: w1t[tap<75][oc<32]
// bf16 weight tables (byte offsets):
#define OFF_W2T_BYTES 737280ul    // 9*64*32   bf16
#define OFF_W3T_BYTES 786432ul    // 9*128*64  bf16
#define OFF_W4T_BYTES 983040ul    // 9*256*128 bf16
#define OFF_EWT_BYTES 2097152ul   // ewt[n=256][k=16384] bf16 = 8 MiB
// post-stage bf16 tables:
#define OFF_NFWT_BYTES 10485760ul // nfwt[n=256][k=256] bf16 = 128 KiB
#define OFF_PJD_BYTES  10616832ul // protos[j][d] bf16
#define OFF_GJD_BYTES  10747904ul // grid[j][d] bf16
#define OFF_PTB_BYTES  10878976ul // protosT[d][j] bf16
// big regions (byte offsets):
#define OFF_A_BYTES   12582912ul
#define OFF_B_BYTES   (OFF_A_BYTES + 67108864ul)
#define OFF_Z0_BYTES  (OFF_B_BYTES + 33554432ul)
// total ~112 MiB

// ---------------- bf16 helpers ----------------
__device__ __forceinline__ float bf2f(ushort u) {
  return __uint_as_float(((unsigned)u) << 16);
}
__device__ __forceinline__ ushort f2bf(float f) {   // RNE
  unsigned x = __float_as_uint(f);
  return (ushort)((x + 0x7fffu + ((x >> 16) & 1u)) >> 16);
}
__device__ __forceinline__ unsigned pack2(float a, float b) {
  return (unsigned)f2bf(a) | ((unsigned)f2bf(b) << 16);
}

// async global->LDS, 16B per lane; lds dest = wave-uniform base + lane*16
__device__ __forceinline__ void gload_lds16(const ushort* g, ushort* l) {
  __builtin_amdgcn_global_load_lds(
      (const __attribute__((address_space(1))) unsigned int*)g,
      (__attribute__((address_space(3))) unsigned int*)l, 16, 0, 0);
}

// ---------------- block reductions ----------------
__device__ __forceinline__ float block_sum(float v, float* red) {
  #pragma unroll
  for (int off = 32; off > 0; off >>= 1) v += __shfl_down(v, off, 64);
  int wid = threadIdx.x >> 6;
  __syncthreads();
  if ((threadIdx.x & 63) == 0) red[wid] = v;
  __syncthreads();
  return red[0] + red[1] + red[2] + red[3];
}

// ---------------- setup (+ zero z0 for split-K atomics) ----------------
__global__ void __launch_bounds__(256) k_setup(const float* __restrict__ protos,
    const float* __restrict__ gridp, const float* __restrict__ gate_logits,
    const float* __restrict__ temp_raw, const float* __restrict__ clf_w,
    float* __restrict__ ws, float* __restrict__ z0) {
  __shared__ float red[4];
  int b = blockIdx.x, t = threadIdx.x;
  #pragma unroll
  for (int u = 0; u < 16; ++u) z0[(size_t)u*65536 + b*256 + t] = 0.f;
  float pv = protos[b*256 + t];
  float gv = gridp [b*256 + t];
  float sp = block_sum(pv*pv, red);
  float sg = block_sum(gv*gv, red);
  if (t == 0) {
    ws[OFF_PN2 + b] = sp;
    ws[OFF_GN2 + b] = sg;
    ws[OFF_GATE + b] = 1.f/(1.f + expf(-gate_logits[b]));
  }
  if (b == 0) {
    for (int i = t; i < 2560; i += TPB) {
      int d = i/10, c = i%10;
      ws[OFF_WEFF + i] = clf_w[d*10+c] + clf_w[(256+d)*10+c]
                       + clf_w[(512+d)*10+c] + clf_w[(768+d)*10+c];
    }
    if (t == 0) {
      float s = 1.f/(1.f + expf(-temp_raw[0]));
      ws[OFF_TEMP] = s*(1.f - 0.001f) + 0.001f;
    }
  }
}

// ---------------- prep: weight tables (conv1 fp32-T, conv2/3/4 bf16) ----------------
__global__ void __launch_bounds__(256) k_prep(const float* __restrict__ w1,
    const float* __restrict__ w2, const float* __restrict__ w3,
    const float* __restrict__ w4, float* __restrict__ w1t,
    ushort* __restrict__ w2t, ushort* __restrict__ w3t, ushort* __restrict__ w4t) {
  int idx = blockIdx.x*256 + threadIdx.x;
  if (idx < 2400) {
    int tap = idx >> 5, oc = idx & 31;
    w1t[idx] = w1[oc*75 + tap];
  }
  if (idx < 18432) {
    int tap = idx >> 11, r = idx & 2047, oc = r >> 5, ic = r & 31;
    w2t[idx] = f2bf(w2[oc*288 + ic*9 + tap]);
  }
  if (idx < 73728) {
    int tap = idx >> 13, r = idx & 8191, oc = r >> 6, ic = r & 63;
    w3t[idx] = f2bf(w3[oc*576 + ic*9 + tap]);
  }
  if (idx < 294912) {
    int tap = idx >> 15, r = idx & 32767, oc = r >> 7, ic = r & 127;
    w4t[idx] = f2bf(w4[oc*1152 + ic*9 + tap]);
  }
}

// ---------------- prep2: bf16 tables for the post stage ----------------
__global__ void __launch_bounds__(256) k_prep2(const float* __restrict__ nfw,
    const float* __restrict__ protos, const float* __restrict__ gridp,
    ushort* __restrict__ nfwt, ushort* __restrict__ pjd,
    ushort* __restrict__ gjd, ushort* __restrict__ ptb) {
  int idx = blockIdx.x*256 + threadIdx.x;   // 65536
  int a = idx >> 8, b = idx & 255;
  nfwt[idx] = f2bf(nfw[b*256 + a]);     // [n][k] = nfw[k][n]
  pjd [idx] = f2bf(protos[idx]);        // [j][d]
  gjd [idx] = f2bf(gridp[idx]);         // [j][d]
  ptb [idx] = f2bf(protos[b*256 + a]);  // [d][j] = protos[j][d]
}

// ---------------- transpose enc_w -> ewt[n<256][k<16384] bf16 ----------------
__global__ void __launch_bounds__(256) k_trans(const float* __restrict__ ew,
    ushort* __restrict__ ewt) {
  __shared__ float tile[64][65];
  int kb = blockIdx.x, nb = blockIdx.y, t = threadIdx.x;
  #pragma unroll
  for (int i = 0; i < 16; ++i) {
    int idx = t + i*256, k = idx >> 6, n = idx & 63;
    tile[k][n] = ew[(size_t)(kb*64 + k)*256 + nb*64 + n];
  }
  __syncthreads();
  #pragma unroll
  for (int i = 0; i < 16; ++i) {
    int idx = t + i*256, n = idx >> 6, k = idx & 63;
    ewt[(size_t)(nb*64 + n)*16384 + kb*64 + k] = f2bf(tile[k][n]);
  }
}

// ---------------- conv1+conv2 fused v4: minimal LDS (xs only, 23.1 KB) ----------
__global__ void __launch_bounds__(256) k_conv12(const float* __restrict__ x,
    const float* __restrict__ w1t, const float* __restrict__ b1,
    const ushort* __restrict__ w2t, const float* __restrict__ b2,
    ushort* __restrict__ h2c) {
  __shared__ ushort xs[17*17*40];   // 23120 B only
  int b = blockIdx.x, t = threadIdx.x;
  for (int i = t; i < 5780; i += TPB) ((unsigned*)xs)[i] = 0u;
  const float* xb = x + (size_t)b*3072;

  if (t < 225) {               // conv1: one px per thread, all 32 oc, packed f32
    int oy = t/15, ox = t%15;
    f32x2 acc[16];
    #pragma unroll
    for (int o = 0; o < 16; ++o) acc[o] = *(const f32x2*)&b1[2*o];
    for (int ic = 0; ic < 3; ++ic) {
      const int icb = ic*1024;
      #pragma unroll
      for (int ky = 0; ky < 5; ++ky) {
        int iy = 2*oy - 1 + ky;
        bool rok = (unsigned)iy < 32u;
        int rbase = icb + (rok ? iy*32 : 0);
        #pragma unroll
        for (int kx = 0; kx < 5; ++kx) {
          int ix = 2*ox - 1 + kx;
          bool ok = rok && ((unsigned)ix < 32u);
          float xv = xb[rbase + (ok ? ix : 0)];
          xv = ok ? xv : 0.f;
          f32x2 xv2 = {xv, xv};
          const float* wrow = &w1t[(ic*25 + ky*5 + kx)*32];   // wave-uniform -> s_load
          #pragma unroll
          for (int g = 0; g < 8; ++g) {
            f32x2 wlo = {wrow[4*g+0], wrow[4*g+1]};
            f32x2 whi = {wrow[4*g+2], wrow[4*g+3]};
            acc[2*g]   += xv2*wlo;
            acc[2*g+1] += xv2*whi;
          }
        }
      }
    }
    unsigned pk[16];
    #pragma unroll
    for (int g = 0; g < 16; ++g)
      pk[g] = pack2(fmaxf(acc[g].x, 0.f), fmaxf(acc[g].y, 0.f));
    ushort* cell = &xs[((oy+1)*17 + (ox+1))*40];
    #pragma unroll
    for (int q = 0; q < 4; ++q) *(uint4*)(cell + q*8) = ((uint4*)pk)[q];
  }
  __syncthreads();

  // conv2 MFMA (swapped: oc-in-regs): wave w -> oc [w*16, w*16+16)
  const int lane = t & 63, w = t >> 6;
  const int quad = lane >> 4, row16 = lane & 15;
  f32x4 acc2[4];
  #pragma unroll
  for (int mt = 0; mt < 4; ++mt) acc2[mt] = (f32x4)0.f;
  #pragma unroll
  for (int ky = 0; ky < 3; ++ky)
    #pragma unroll
    for (int kx = 0; kx < 3; ++kx) {
      int tap = ky*3 + kx;
      bf16x8 bf = *(const bf16x8*)&w2t[tap*2048 + (w*16 + row16)*32 + quad*8];
      #pragma unroll
      for (int mt = 0; mt < 4; ++mt) {
        int px = mt*16 + row16;
        int iy = 2*(px >> 3) + ky, ix = 2*(px & 7) + kx;
        bf16x8 af = *(const bf16x8*)&xs[(iy*17 + ix)*40 + quad*8];
        acc2[mt] = __builtin_amdgcn_mfma_f32_16x16x32_bf16(bf, af, acc2[mt], 0, 0, 0);
      }
    }
  float4 bb = *(const float4*)&b2[w*16 + quad*4];
  #pragma unroll
  for (int mt = 0; mt < 4; ++mt) {
    int px = mt*16 + row16;
    uint2 dd;
    dd.x = pack2(fmaxf(acc2[mt][0] + bb.x, 0.f), fmaxf(acc2[mt][1] + bb.y, 0.f));
    dd.y = pack2(fmaxf(acc2[mt][2] + bb.z, 0.f), fmaxf(acc2[mt][3] + bb.w, 0.f));
    *(uint2*)&h2c[(size_t)b*4096 + px*64 + w*16 + quad*4] = dd;
  }
}

// ---------------- conv3+conv4 fused v6: 2 imgs/block, B shared, xp/h3p ALIASED,
// NO VGPR cap (launch_bounds 256,2 -> natural 128 regs; 34.8 KB LDS -> 4 blk/CU) ----
__global__ void __launch_bounds__(256, 2) k_conv34(const ushort* __restrict__ h2c,
    const float* __restrict__ b3, const float* __restrict__ b4,
    const ushort* __restrict__ w3t, const ushort* __restrict__ w4t,
    ushort* __restrict__ h4c, int img_base) {
  __shared__ ushort buf[2*8704];    // 34816 B total
  ushort* xp  = buf;                // [img*4608 + px*72 + ic]   (18432 B)
  ushort* h3p = buf;                // [img*8704 + px*136 + oc]  (34816 B, after alias barrier)
  const int bl = blockIdx.x, t = threadIdx.x;
  #pragma unroll
  for (int u = 0; u < 4; ++u) {
    int i = t + u*256;
    int img = i >> 9, r = i & 511, px = r >> 3, icq = r & 7;
    bf16x8 v = *(const bf16x8*)&h2c[(size_t)(img_base + bl*2 + img)*4096 + px*64 + icq*8];
    *(bf16x8*)&xp[img*4608 + px*72 + icq*8] = v;
  }
  __syncthreads();

  const int lane = t & 63, oq = t >> 6;
  const int quad = lane >> 4, row16 = lane & 15;
  const bf16x8 zr = (bf16x8)(short)0;
  int aoy[8], aox[8], ioff3[8], ioff4[8];
  #pragma unroll
  for (int mt = 0; mt < 8; ++mt) {
    int px = (mt & 3)*16 + row16;
    aoy[mt] = px >> 3; aox[mt] = px & 7;
    ioff3[mt] = (mt >> 2)*4608;
    ioff4[mt] = (mt >> 2)*8704;
  }

  // ---- conv3 (reads xp view) ----
  f32x4 c3[8][2];
  #pragma unroll
  for (int mt = 0; mt < 8; ++mt) { c3[mt][0] = (f32x4)0.f; c3[mt][1] = (f32x4)0.f; }
  const ushort* wb3 = w3t + (oq*32 + row16)*64 + quad*8;
  bf16x8 r3a = *(const bf16x8*)(wb3);
  bf16x8 r3b = *(const bf16x8*)(wb3 + 1024);
  for (int tap = 0; tap < 9; ++tap, wb3 += 8192) {
    int ky = tap/3, kx = tap - 3*ky;
    int ab[8]; bool vv[8];
    #pragma unroll
    for (int mt = 0; mt < 8; ++mt) {
      int iy = aoy[mt] + ky - 1, ix = aox[mt] + kx - 1;
      vv[mt] = ((unsigned)iy < 8u) && ((unsigned)ix < 8u);
      int pxv = vv[mt] ? (iy*8 + ix) : 0;
      ab[mt] = ioff3[mt] + pxv*72 + quad*8;
    }
    #pragma unroll
    for (int ks = 0; ks < 2; ++ks) {
      const ushort* wn = wb3 + ((ks == 1) ? 8192 : 32);
      bf16x8 n0 = *(const bf16x8*)(wn);
      bf16x8 n1 = *(const bf16x8*)(wn + 1024);
      #pragma unroll
      for (int mt = 0; mt < 8; ++mt) {
        bf16x8 ax = *(const bf16x8*)&xp[ab[mt] + ks*32];
        ax = vv[mt] ? ax : zr;
        c3[mt][0] = __builtin_amdgcn_mfma_f32_16x16x32_bf16(r3a, ax, c3[mt][0], 0, 0, 0);
        c3[mt][1] = __builtin_amdgcn_mfma_f32_16x16x32_bf16(r3b, ax, c3[mt][1], 0, 0, 0);
      }
      r3a = n0; r3b = n1;
    }
  }
  __syncthreads();   // ALIAS BARRIER: all xp reads complete before h3p overwrites buf
  #pragma unroll
  for (int nt = 0; nt < 2; ++nt) {
    float4 bb = *(const float4*)&b3[oq*32 + nt*16 + quad*4];
    #pragma unroll
    for (int mt = 0; mt < 8; ++mt) {
      int px = (mt & 3)*16 + row16;
      uint2 dd;
      dd.x = pack2(fmaxf(c3[mt][nt][0] + bb.x, 0.f), fmaxf(c3[mt][nt][1] + bb.y, 0.f));
      dd.y = pack2(fmaxf(c3[mt][nt][2] + bb.z, 0.f), fmaxf(c3[mt][nt][3] + bb.w, 0.f));
      *(uint2*)&h3p[ioff4[mt] + px*136 + oq*32 + nt*16 + quad*4] = dd;
    }
  }
  __syncthreads();

  // ---- conv4 (reads h3p view) ----
  f32x4 c4[8][4];
  #pragma unroll
  for (int mt = 0; mt < 8; ++mt)
    #pragma unroll
    for (int nt = 0; nt < 4; ++nt) c4[mt][nt] = (f32x4)0.f;
  const ushort* wb4 = w4t + (oq*64 + row16)*128 + quad*8;
  bf16x8 r4[4];
  #pragma unroll
  for (int nt = 0; nt < 4; ++nt) r4[nt] = *(const bf16x8*)(wb4 + nt*2048);
  for (int tap = 0; tap < 9; ++tap, wb4 += 32768) {
    int ky = tap/3, kx = tap - 3*ky;
    int ab[8]; bool vv[8];
    #pragma unroll
    for (int mt = 0; mt < 8; ++mt) {
      int iy = aoy[mt] + ky - 1, ix = aox[mt] + kx - 1;
      vv[mt] = ((unsigned)iy < 8u) && ((unsigned)ix < 8u);
      int pxv = vv[mt] ? (iy*8 + ix) : 0;
      ab[mt] = ioff4[mt] + pxv*136 + quad*8;
    }
    #pragma unroll
    for (int ks = 0; ks < 4; ++ks) {
      const ushort* wn = wb4 + ((ks == 3) ? 32768 : (ks + 1)*32);
      bf16x8 nx[4];
      #pragma unroll
      for (int nt = 0; nt < 4; ++nt) nx[nt] = *(const bf16x8*)(wn + nt*2048);
      #pragma unroll
      for (int mt = 0; mt < 8; ++mt) {
        bf16x8 ax = *(const bf16x8*)&h3p[ab[mt] + ks*32];
        ax = vv[mt] ? ax : zr;
        #pragma unroll
        for (int nt = 0; nt < 4; ++nt)
          c4[mt][nt] = __builtin_amdgcn_mfma_f32_16x16x32_bf16(ax, r4[nt], c4[mt][nt], 0, 0, 0);
      }
      #pragma unroll
      for (int nt = 0; nt < 4; ++nt) r4[nt] = nx[nt];
    }
  }
  #pragma unroll
  for (int nt = 0; nt < 4; ++nt) {
    int oc = oq*64 + nt*16 + row16;
    float bv = b4[oc];
    #pragma unroll
    for (int mt = 0; mt < 8; ++mt) {
      int ig = bl*2 + (mt >> 2);
      int px0 = (mt & 3)*16 + quad*4;
      uint2 dd;
      dd.x = pack2(fmaxf(c4[mt][nt][0] + bv, 0.f), fmaxf(c4[mt][nt][1] + bv, 0.f));
      dd.y = pack2(fmaxf(c4[mt][nt][2] + bv, 0.f), fmaxf(c4[mt][nt][3] + bv, 0.f));
      *(uint2*)&h4c[(size_t)ig*16384 + oc*64 + px0] = dd;
    }
  }
}

// ---------------- enc: z0 += h4c @ ewt^T, MFMA bf16, split-K=16, 128x128 tiles ------
__global__ void __launch_bounds__(256) k_enc(const ushort* __restrict__ h4c,
    const ushort* __restrict__ ewt, float* __restrict__ z0, int img_base) {
  __shared__ ushort a_s[128*64];   // 16 KB
  __shared__ ushort b_s[128*64];   // 16 KB
  const int t = threadIdx.x, bx = blockIdx.x;
  const int slice = bx & 15;
  const int mb = (bx >> 4) & 15;
  const int nb = bx >> 8;
  const int M0 = mb*128, N0 = nb*128;
  const int kbase = slice*1024;
  const int lane = t & 63, wv = t >> 6;
  const int quad = lane >> 4, row16 = lane & 15;
  const int mrow0 = (wv & 1)*64, ncol0 = (wv >> 1)*64;
  const int sr = lane >> 3, sp = lane & 7;

  f32x4 acc[4][4];
  #pragma unroll
  for (int mt = 0; mt < 4; ++mt)
    #pragma unroll
    for (int nt = 0; nt < 4; ++nt) acc[mt][nt] = (f32x4)0.f;

  for (int kt = 0; kt < 16; ++kt) {
    const int k0 = kbase + kt*64;
    __syncthreads();
    #pragma unroll
    for (int u = 0; u < 4; ++u) {
      int r = wv*32 + u*8 + sr;
      int c = sp ^ (r & 7);
      gload_lds16(&h4c[(size_t)(M0 + r)*16384 + k0 + c*8], &a_s[(wv*32 + u*8)*64]);
      gload_lds16(&ewt[(size_t)(N0 + r)*16384 + k0 + c*8], &b_s[(wv*32 + u*8)*64]);
    }
    __syncthreads();
    #pragma unroll
    for (int ks = 0; ks < 2; ++ks) {
      bf16x8 af[4], bf[4];
      #pragma unroll
      for (int mt = 0; mt < 4; ++mt) {
        int r = mrow0 + mt*16 + row16;
        int p = (ks*4 + quad) ^ (r & 7);
        af[mt] = *(const bf16x8*)&a_s[r*64 + p*8];
      }
      #pragma unroll
      for (int nt = 0; nt < 4; ++nt) {
        int r = ncol0 + nt*16 + row16;
        int p = (ks*4 + quad) ^ (r & 7);
        bf[nt] = *(const bf16x8*)&b_s[r*64 + p*8];
      }
      #pragma unroll
      for (int mt = 0; mt < 4; ++mt)
        #pragma unroll
        for (int nt = 0; nt < 4; ++nt)
          acc[mt][nt] = __builtin_amdgcn_mfma_f32_16x16x32_bf16(af[mt], bf[nt], acc[mt][nt], 0, 0, 0);
    }
  }
  #pragma unroll
  for (int mt = 0; mt < 4; ++mt) {
    int mrow = M0 + mrow0 + mt*16 + quad*4;
    #pragma unroll
    for (int nt = 0; nt < 4; ++nt) {
      int col = N0 + ncol0 + nt*16 + row16;
      #pragma unroll
      for (int r = 0; r < 4; ++r)
        atomicAdd(&z0[(size_t)(img_base + mrow + r)*256 + col], acc[mt][nt][r]);
    }
  }
}

// ---------------- post v2: fully-fused MFMA tail, 16 img/block, grid 256 ----------
__global__ void __launch_bounds__(256) k_post2(const float* __restrict__ z0,
    const float* __restrict__ enc_b, const float* __restrict__ nfb,
    const ushort* __restrict__ nfwt, const ushort* __restrict__ pjd,
    const ushort* __restrict__ gjd, const ushort* __restrict__ ptb,
    const float* __restrict__ ws, const float* __restrict__ clf_b,
    float* __restrict__ out) {
  __shared__ ushort zin[16*264];   // 8448 B
  __shared__ ushort zS [16*264];   // 8448 B
  __shared__ float  Df [16*264];   // 16896 B (l / blended)
  __shared__ ushort wS [16*264];   // 8448 B
  __shared__ float  z2s[16];
  const int t = threadIdx.x, bx = blockIdx.x;
  const int img0 = bx*16;
  #pragma unroll
  for (int u = 0; u < 16; ++u) {
    int i = t + u*256;
    int im = i >> 8, d = i & 255;
    zin[im*264 + d] = f2bf(z0[(size_t)(img0 + im)*256 + d] + enc_b[d]);
  }
  __syncthreads();

  const int lane = t & 63, w = t >> 6;
  const int quad = lane >> 4, row16 = lane & 15;
  const int n0 = w*64;

  // ---- phase 1: z = zin @ nfw^T + nfb ----
  f32x4 zC[4];
  #pragma unroll
  for (int nt = 0; nt < 4; ++nt) zC[nt] = (f32x4)0.f;
  #pragma unroll
  for (int ks = 0; ks < 8; ++ks) {
    bf16x8 az = *(const bf16x8*)&zin[row16*264 + ks*32 + quad*8];
    #pragma unroll
    for (int nt = 0; nt < 4; ++nt) {
      bf16x8 bw = *(const bf16x8*)&nfwt[(n0 + nt*16 + row16)*256 + ks*32 + quad*8];
      zC[nt] = __builtin_amdgcn_mfma_f32_16x16x32_bf16(az, bw, zC[nt], 0, 0, 0);
    }
  }
  #pragma unroll
  for (int nt = 0; nt < 4; ++nt) {
    int n = n0 + nt*16 + row16;
    float nb = nfb[n];
    #pragma unroll
    for (int r = 0; r < 4; ++r)
      zS[(quad*4 + r)*264 + n] = f2bf(zC[nt][r] + nb);
  }
  __syncthreads();

  {
    int im = t >> 4, jg = t & 15;
    float s = 0.f;
    #pragma unroll
    for (int q = 0; q < 16; ++q) {
      float v = bf2f(zS[im*264 + jg + 16*q]);
      s += v*v;
    }
    #pragma unroll
    for (int off = 8; off; off >>= 1) s += __shfl_xor(s, off, 16);
    if (jg == 0) z2s[im] = s;
  }
  __syncthreads();

  // ---- phase 2: dp/dg = z @ protos^T / grid^T -> logits l ----
  f32x4 dpC[4], dgC[4];
  #pragma unroll
  for (int nt = 0; nt < 4; ++nt) { dpC[nt] = (f32x4)0.f; dgC[nt] = (f32x4)0.f; }
  #pragma unroll
  for (int ks = 0; ks < 8; ++ks) {
    bf16x8 az = *(const bf16x8*)&zS[row16*264 + ks*32 + quad*8];
    #pragma unroll
    for (int nt = 0; nt < 4; ++nt) {
      int j = n0 + nt*16 + row16;
      bf16x8 bp = *(const bf16x8*)&pjd[j*256 + ks*32 + quad*8];
      bf16x8 bg = *(const bf16x8*)&gjd[j*256 + ks*32 + quad*8];
      dpC[nt] = __builtin_amdgcn_mfma_f32_16x16x32_bf16(az, bp, dpC[nt], 0, 0, 0);
      dgC[nt] = __builtin_amdgcn_mfma_f32_16x16x32_bf16(az, bg, dgC[nt], 0, 0, 0);
    }
  }
  {
    float temp = ws[OFF_TEMP];
    #pragma unroll
    for (int nt = 0; nt < 4; ++nt) {
      int j = n0 + nt*16 + row16;
      float pn = ws[OFF_PN2 + j], gn = ws[OFF_GN2 + j];
      #pragma unroll
      for (int r = 0; r < 4; ++r) {
        int im = quad*4 + r;
        float z2 = z2s[im];
        float d2p = z2 + pn - 2.f*dpC[nt][r];
        float d2g = z2 + gn - 2.f*dgC[nt][r];
        float l = -(sqrtf(fmaxf(d2p, 0.f)) + sqrtf(fmaxf(d2g, 0.f)))/temp;
        Df[im*264 + j] = l;
      }
    }
  }
  __syncthreads();

  // ---- softmax + gate + renorm -> wS bf16 ----
  {
    int im = t >> 4, jg = t & 15;
    float m = -1e30f;
    #pragma unroll
    for (int q = 0; q < 16; ++q) m = fmaxf(m, Df[im*264 + jg + 16*q]);
    #pragma unroll
    for (int off = 8; off; off >>= 1) m = fmaxf(m, __shfl_xor(m, off, 16));
    float E = 0.f, S = 0.f, ev[16], gv[16];
    #pragma unroll
    for (int q = 0; q < 16; ++q) {
      int j = jg + 16*q;
      float e = expf(Df[im*264 + j] - m);
      float g = ws[OFF_GATE + j];
      ev[q] = e; gv[q] = g;
      E += e; S += e*g;
    }
    #pragma unroll
    for (int off = 8; off; off >>= 1) {
      E += __shfl_xor(E, off, 16);
      S += __shfl_xor(S, off, 16);
    }
    float inv = 1.f/(S + 1e-8f*E);
    #pragma unroll
    for (int q = 0; q < 16; ++q)
      wS[im*264 + jg + 16*q] = f2bf(ev[q]*gv[q]*inv);
  }
  __syncthreads();

  // ---- phase 3: blended = w @ protos ----
  f32x4 blC[4];
  #pragma unroll
  for (int nt = 0; nt < 4; ++nt) blC[nt] = (f32x4)0.f;
  #pragma unroll
  for (int ks = 0; ks < 8; ++ks) {
    bf16x8 aw = *(const bf16x8*)&wS[row16*264 + ks*32 + quad*8];
    #pragma unroll
    for (int nt = 0; nt < 4; ++nt) {
      bf16x8 bp = *(const bf16x8*)&ptb[(n0 + nt*16 + row16)*256 + ks*32 + quad*8];
      blC[nt] = __builtin_amdgcn_mfma_f32_16x16x32_bf16(aw, bp, blC[nt], 0, 0, 0);
    }
  }
  #pragma unroll
  for (int nt = 0; nt < 4; ++nt) {
    int d = n0 + nt*16 + row16;
    #pragma unroll
    for (int r = 0; r < 4; ++r)
      Df[(quad*4 + r)*264 + d] = blC[nt][r];
  }
  __syncthreads();

  if (t < 160) {
    int im = t/10, c = t - im*10;
    float s = clf_b[c];
    for (int d = 0; d < 256; ++d)
      s += Df[im*264 + d]*ws[OFF_WEFF + d*10 + c];
    out[(size_t)(img0 + im)*10 + c] = s;
  }
}

extern "C" void kernel_launch(void* const* d_in, const int* in_sizes, int n_in,
                              void* d_out, int out_size, void* d_ws, size_t ws_size,
                              hipStream_t stream) {
  (void)in_sizes; (void)n_in; (void)out_size; (void)ws_size;
  const float* x      = (const float*)d_in[0];
  const float* c1w    = (const float*)d_in[2];
  const float* c1b    = (const float*)d_in[3];
  const float* c2w    = (const float*)d_in[4];
  const float* c2b    = (const float*)d_in[5];
  const float* c3w    = (const float*)d_in[6];
  const float* c3b    = (const float*)d_in[7];
  const float* c4w    = (const float*)d_in[8];
  const float* c4b    = (const float*)d_in[9];
  const float* encw   = (const float*)d_in[10];
  const float* encb   = (const float*)d_in[11];
  // d_in[12..17] dead: softmax over a single node == 1 exactly
  const float* clfw   = (const float*)d_in[18];
  const float* clfb   = (const float*)d_in[19];
  const float* nfw    = (const float*)d_in[20];
  const float* nfb    = (const float*)d_in[21];
  const float* protos = (const float*)d_in[22];
  const float* gridp  = (const float*)d_in[23];
  const float* traw   = (const float*)d_in[24];
  const float* gatel  = (const float*)d_in[25];

  float*  ws   = (float*)d_ws;
  float*  w1t  = ws + OFF_W1T;
  ushort* w2t  = (ushort*)((char*)d_ws + OFF_W2T_BYTES);
  ushort* w3t  = (ushort*)((char*)d_ws + OFF_W3T_BYTES);
  ushort* w4t  = (ushort*)((char*)d_ws + OFF_W4T_BYTES);
  ushort* ewt  = (ushort*)((char*)d_ws + OFF_EWT_BYTES);
  ushort* nfwt = (ushort*)((char*)d_ws + OFF_NFWT_BYTES);
  ushort* pjd  = (ushort*)((char*)d_ws + OFF_PJD_BYTES);
  ushort* gjd  = (ushort*)((char*)d_ws + OFF_GJD_BYTES);
  ushort* ptb  = (ushort*)((char*)d_ws + OFF_PTB_BYTES);
  ushort* h4c  = (ushort*)((char*)d_ws + OFF_A_BYTES);
  ushort* h2c  = (ushort*)((char*)d_ws + OFF_B_BYTES);
  float*  z0   = (float*) ((char*)d_ws + OFF_Z0_BYTES);
  float*  out  = (float*)d_out;

  hipLaunchKernelGGL(k_setup, dim3(256),  dim3(TPB), 0, stream, protos, gridp, gatel, traw, clfw, ws, z0);
  hipLaunchKernelGGL(k_prep,  dim3(1152), dim3(TPB), 0, stream, c1w, c2w, c3w, c4w, w1t, w2t, w3t, w4t);
  hipLaunchKernelGGL(k_prep2, dim3(256),  dim3(TPB), 0, stream, nfw, protos, gridp, nfwt, pjd, gjd, ptb);
  hipLaunchKernelGGL(k_trans, dim3(256, 4), dim3(TPB), 0, stream, encw, ewt);
  hipLaunchKernelGGL(k_conv12, dim3(4096), dim3(TPB), 0, stream, x, w1t, c1b, w2t, c2b, h2c);
  for (int c = 0; c < 2; ++c) {
    hipLaunchKernelGGL(k_conv34, dim3(1024), dim3(TPB), 0, stream,
                       h2c, c3b, c4b, w3t, w4t, h4c, c*2048);
    hipLaunchKernelGGL(k_enc, dim3(512), dim3(TPB), 0, stream, h4c, ewt, z0, c*2048);
  }
  hipLaunchKernelGGL(k_post2, dim3(256), dim3(TPB), 0, stream,
                     z0, encb, nfb, nfwt, pjd, gjd, ptb, ws, clfb, out);
}